// Round 1
// baseline (423.316 us; speedup 1.0000x reference)
//
#include <hip/hip_runtime.h>
#include <hip/hip_cooperative_groups.h>

namespace cg = cooperative_groups;

#define NN   2048
#define F0D  128
#define HIDD 64
#define OUTD 16
#define KDEG 10

// ws float layout: [0] p-ping (2048) | [2048] p-pong (2048) | [4096] weff (2048)
//                  | [6144] Hg (512)
//
// One block per CU. Block g owns columns u0=g*8..g*8+7: its 2048x8 slice of L
// (64 KB) stays in LDS for the whole kernel, so the 10 serial L^T-matvecs are
// LDS-resident with one grid.sync() each instead of 10 kernel launches that
// each re-stream 16.78 MB of L.

__global__ __launch_bounds__(256, 1) void k_fused(
    const float* __restrict__ X, const float* __restrict__ L,
    const float* __restrict__ W1, const float* __restrict__ b1,
    const float* __restrict__ W2, const float* __restrict__ b2,
    const float* __restrict__ theta, float* __restrict__ out,
    float* __restrict__ ws)
{
    cg::grid_group grid = cg::this_grid();

    float* bufs0 = ws;            // p ping
    float* bufs1 = ws + NN;       // p pong
    float* weff  = ws + 2 * NN;   // g(L)^T 1
    float* Hg    = ws + 3 * NN;   // 8*64

    __shared__ union {
        struct { float Lt[NN * 8]; float red[4][8]; float cb[16]; } mv;
        struct { float W1t[64][132]; float redm[16][65]; float wv[64]; } hd;
    } sm;

    const int g  = blockIdx.x;    // 256 blocks
    const int t  = threadIdx.x;   // 256 threads
    const int u0 = g * 8;

    // Bernstein -> monomial coefficients c[0..K] (redundant per block, tiny)
    if (t <= KDEG) {
        const float C10[11] = {1,10,45,120,210,252,210,120,45,10,1};
        float acc = 0.f;
        for (int i = 0; i <= t; ++i) {
            int n = KDEG - i, r = t - i;
            long long cm = 1;
            for (int s = 1; s <= r; ++s) cm = cm * (n - r + s) / s;  // exact
            float term = theta[i] * C10[i] * (float)cm;
            if ((t - i) & 1) term = -term;
            acc += term;
        }
        sm.mv.cb[t] = acc;
    }
    if (g == 0) { Hg[t] = 0.f; Hg[t + 256] = 0.f; }  // visible after sync #1..10

    // Load L[:, u0:u0+8] into LDS (64 KB): 32 B per row per block.
    const float4* L4  = (const float4*)L;          // row stride NN/4
    float4*       Lt4 = (float4*)sm.mv.Lt;
    const int half = t & 1, vb = t >> 1;
    const int colbase = (u0 >> 2) + half;
    #pragma unroll
    for (int i = 0; i < 16; ++i) {
        int v = vb + 128 * i;
        Lt4[v * 2 + half] = L4[(size_t)v * (NN / 4) + colbase];
    }
    __syncthreads();

    // p_j = (L^T)^j 1 ; w = sum_{j<K} c_j p_j ; weff = w + c_K p_K
    float wacc = 0.f;   // meaningful on t < 8 (one u per thread)
    for (int j = 1; j <= KDEG; ++j) {
        const float* xcur = ((j - 1) & 1) ? bufs1 : bufs0;
        float*       xnxt = (j & 1) ? bufs1 : bufs0;
        float4 acc = make_float4(0.f, 0.f, 0.f, 0.f);
        #pragma unroll
        for (int k = 0; k < 16; ++k) {
            int v = vb + 128 * k;
            float xv = (j == 1) ? 1.0f : xcur[v];     // p_0 = ones, no load
            float4 lv = Lt4[v * 2 + half];            // conflict-free b128
            acc.x += lv.x * xv; acc.y += lv.y * xv;
            acc.z += lv.z * xv; acc.w += lv.w * xv;
        }
        // reduce over vb within wave (lanes stride 2; bit0 = u-half, keep)
        #pragma unroll
        for (int m = 2; m <= 32; m <<= 1) {
            acc.x += __shfl_xor(acc.x, m); acc.y += __shfl_xor(acc.y, m);
            acc.z += __shfl_xor(acc.z, m); acc.w += __shfl_xor(acc.w, m);
        }
        int lane = t & 63, wvi = t >> 6;
        if (lane < 2) *(float4*)&sm.mv.red[wvi][lane * 4] = acc;
        __syncthreads();
        if (t < 8) {
            float s = sm.mv.red[0][t] + sm.mv.red[1][t]
                    + sm.mv.red[2][t] + sm.mv.red[3][t];
            float pprev = (j == 1) ? 1.0f : xcur[u0 + t];
            wacc += sm.mv.cb[j - 1] * pprev;
            if (j < KDEG) xnxt[u0 + t] = s;                       // p_j out
            else          weff[u0 + t] = wacc + sm.mv.cb[KDEG] * s;
        }
        grid.sync();
    }

    // Head: Hg[b,h] += (1/N) sum_v weff[v] * relu(X[b,v,:] @ W1[:,h] + b1[h])
    // Remap: 256 blocks -> (b = g>>5, vchunk = g&31, 64 v each). LDS reused.
    const int b = g >> 5, vchunk = g & 31;
    for (int i = t; i < F0D * HIDD; i += 256) {
        int f = i >> 6, h = i & 63;
        sm.hd.W1t[h][f] = W1[i];
    }
    if (t < 64) sm.hd.wv[t] = weff[vchunk * 64 + t];
    __syncthreads();

    int hg = t & 15, vg = t >> 4;
    int vbase = vchunk * 64 + vg * 4;
    const float* Xb = X + ((size_t)b * NN + vbase) * F0D;
    float acc2[4][4] = {};
    for (int f = 0; f < F0D; f += 4) {
        float4 xr[4];
        #pragma unroll
        for (int i = 0; i < 4; ++i)
            xr[i] = *(const float4*)(Xb + (size_t)i * F0D + f);
        #pragma unroll
        for (int jj = 0; jj < 4; ++jj) {
            float4 wr = *(const float4*)(&sm.hd.W1t[hg + 16 * jj][f]);
            #pragma unroll
            for (int i = 0; i < 4; ++i)
                acc2[i][jj] += xr[i].x * wr.x + xr[i].y * wr.y
                             + xr[i].z * wr.z + xr[i].w * wr.w;
        }
    }
    float hsum[4] = {0.f, 0.f, 0.f, 0.f};
    #pragma unroll
    for (int i = 0; i < 4; ++i) {
        float we = sm.hd.wv[vg * 4 + i];
        #pragma unroll
        for (int jj = 0; jj < 4; ++jj) {
            float r = acc2[i][jj] + b1[hg + 16 * jj];
            r = r > 0.f ? r : 0.f;
            hsum[jj] += r * we;
        }
    }
    #pragma unroll
    for (int jj = 0; jj < 4; ++jj) sm.hd.redm[vg][hg + 16 * jj] = hsum[jj];
    __syncthreads();
    if (t < 64) {
        float s = 0.f;
        #pragma unroll
        for (int i = 0; i < 16; ++i) s += sm.hd.redm[i][t];
        atomicAdd(&Hg[b * 64 + t], s * (1.0f / (float)NN));
    }
    grid.sync();

    // out = Hg @ W2 + b2  (block 0, 128 threads' worth of work)
    if (g == 0 && t < 128) {
        int o = t & 15, bb = t >> 4;
        float acc3 = b2[o];
        #pragma unroll
        for (int h = 0; h < HIDD; ++h)
            acc3 += Hg[bb * 64 + h] * W2[h * 16 + o];
        out[bb * 16 + o] = acc3;
    }
}

extern "C" void kernel_launch(void* const* d_in, const int* in_sizes, int n_in,
                              void* d_out, int out_size, void* d_ws, size_t ws_size,
                              hipStream_t stream) {
    const float* X     = (const float*)d_in[0];
    const float* L     = (const float*)d_in[1];
    const float* W1    = (const float*)d_in[2];
    const float* b1    = (const float*)d_in[3];
    const float* W2    = (const float*)d_in[4];
    const float* b2    = (const float*)d_in[5];
    const float* theta = (const float*)d_in[6];
    // d_in[7] = dp = 0 -> dropout identity; ignored.
    float* outp = (float*)d_out;
    float* wsp  = (float*)d_ws;

    void* args[] = {(void*)&X, (void*)&L, (void*)&W1, (void*)&b1,
                    (void*)&W2, (void*)&b2, (void*)&theta, (void*)&outp, (void*)&wsp};
    hipLaunchCooperativeKernel((void*)k_fused, dim3(256), dim3(256),
                               args, 0, stream);
}

// Round 2
// 305.186 us; speedup vs baseline: 1.3871x; 1.3871x over previous
//
#include <hip/hip_runtime.h>
#include <hip/hip_cooperative_groups.h>

#define NN     2048
#define F0D    128
#define HIDD   64
#define OUTD   16
#define KDEG   10
#define NCHAIN 128      // blocks participating in the matvec chain
#define COLS   16       // L columns owned per chain block (2048x16 fp32 = 128 KB LDS)

// ws float layout:
//  [0]    p ping (2048)
//  [2048] p pong (2048)
//  [4096] weff   (2048)
//  [6144] Hg     (512)
//  [6656] barrier root (uint)
//  [6688 + 32*grp] 8 group counters (one cache line apart)
// memset region: floats [6144, 7168) zeroed per launch.

// ---- custom monotonic-epoch barrier (two-level: 8 groups -> root) ----
__device__ __forceinline__ void bar_arrive(float* ws, int g) {
    __threadfence();
    unsigned* grp = (unsigned*)(ws + 6688 + 32 * (g & 7));
    unsigned old = __hip_atomic_fetch_add(grp, 1u, __ATOMIC_RELEASE,
                                          __HIP_MEMORY_SCOPE_AGENT);
    if ((old & 15u) == 15u)   // every 16th arrival in a group forwards 16
        __hip_atomic_fetch_add((unsigned*)(ws + 6656), 16u, __ATOMIC_RELEASE,
                               __HIP_MEMORY_SCOPE_AGENT);
}
__device__ __forceinline__ void bar_wait(float* ws, unsigned target) {
    unsigned* root = (unsigned*)(ws + 6656);
    while (__hip_atomic_load(root, __ATOMIC_ACQUIRE,
                             __HIP_MEMORY_SCOPE_AGENT) < target)
        __builtin_amdgcn_s_sleep(4);
    __threadfence();
}

__global__ __launch_bounds__(256, 1) void k_fused(
    const float* __restrict__ X, const float* __restrict__ L,
    const float* __restrict__ W1, const float* __restrict__ b1,
    const float* __restrict__ W2, const float* __restrict__ b2,
    const float* __restrict__ theta, float* __restrict__ out,
    float* __restrict__ ws)
{
    float* bp0  = ws;
    float* bp1  = ws + NN;
    float* weff = ws + 2 * NN;
    float* Hg   = ws + 3 * NN;

    __shared__ union {
        struct { float Lt[NN * COLS]; float xs[NN]; float redf[4][16]; float cbv[16]; } mv;
        struct { float W1t[64][132]; float redm[16][65]; float wv[64]; } hd;
    } sm;

    const int g = blockIdx.x;   // 256 blocks
    const int t = threadIdx.x;  // 256 threads

    if (g < NCHAIN) {
        // ---------------- chain phase: weff = sum_j c_j (L^T)^j 1 ----------------
        const int u0 = g * COLS;

        // Bernstein -> monomial coefficients (exact integer binomials)
        if (t <= KDEG) {
            const float C10[11] = {1,10,45,120,210,252,210,120,45,10,1};
            float acc = 0.f;
            for (int i = 0; i <= t; ++i) {
                int n = KDEG - i, r = t - i;
                long long cm = 1;
                for (int s = 1; s <= r; ++s) cm = cm * (n - r + s) / s;
                float term = theta[i] * C10[i] * (float)cm;
                if ((t - i) & 1) term = -term;
                acc += term;
            }
            sm.mv.cbv[t] = acc;
        }

        // Load L[:, u0:u0+16] into LDS: 64 B per row, 64B-aligned segments.
        const float4* L4  = (const float4*)L;        // row stride NN/4
        float4*       Lt4 = (float4*)sm.mv.Lt;
        #pragma unroll 8
        for (int i = 0; i < 32; ++i) {
            int idx = t + 256 * i;                   // 8192 float4s total
            int v = idx >> 2, qc = idx & 3;
            Lt4[idx] = L4[(size_t)v * (NN / 4) + (u0 >> 2) + qc];
        }
        __syncthreads();

        float wacc = 0.f;   // on t < COLS: Horner accumulation sum_{j<K} c_j p_j[u0+t]
        for (int j = 1; j <= KDEG; ++j) {
            if (j > 1) { if (t == 0) bar_wait(ws, 128u * (j - 1)); __syncthreads(); }

            // stage p_{j-1} into LDS (agent-scope loads: always coherent)
            if (j > 1) {
                const unsigned long long* xg =
                    (const unsigned long long*)(((j - 1) & 1) ? bp1 : bp0);
                unsigned long long* xsd = (unsigned long long*)sm.mv.xs;
                #pragma unroll
                for (int i = 0; i < 4; ++i)
                    xsd[t + 256 * i] = __hip_atomic_load(&xg[t + 256 * i],
                        __ATOMIC_RELAXED, __HIP_MEMORY_SCOPE_AGENT);
            }
            __syncthreads();

            // y[u0+c] = sum_v Lt[v][c] * x[v]; thread = (qc = c/4, r = row stream)
            const int qc = t & 3, r = t >> 2;        // 64 row-streams x 4 col-quads
            float4 acc = make_float4(0.f, 0.f, 0.f, 0.f);
            #pragma unroll 8
            for (int k = 0; k < 32; ++k) {
                int v = r + 64 * k;
                float xv = (j == 1) ? 1.0f : sm.mv.xs[v];
                float4 lv = Lt4[v * 4 + qc];         // conflict-free b128
                acc.x += lv.x * xv; acc.y += lv.y * xv;
                acc.z += lv.z * xv; acc.w += lv.w * xv;
            }
            // reduce the 16 row-streams within each wave (lane bits 2..5)
            #pragma unroll
            for (int m = 4; m <= 32; m <<= 1) {
                acc.x += __shfl_xor(acc.x, m); acc.y += __shfl_xor(acc.y, m);
                acc.z += __shfl_xor(acc.z, m); acc.w += __shfl_xor(acc.w, m);
            }
            int lane = t & 63, wid = t >> 6;
            if (lane < 4) *(float4*)&sm.mv.redf[wid][lane * 4] = acc;
            __syncthreads();

            if (t < COLS) {
                float s = sm.mv.redf[0][t] + sm.mv.redf[1][t]
                        + sm.mv.redf[2][t] + sm.mv.redf[3][t];
                float pprev = (j == 1) ? 1.0f : sm.mv.xs[u0 + t];
                wacc += sm.mv.cbv[j - 1] * pprev;
                if (j < KDEG) {
                    float* xn = (j & 1) ? bp1 : bp0;
                    __hip_atomic_store(&xn[u0 + t], s, __ATOMIC_RELAXED,
                                       __HIP_MEMORY_SCOPE_AGENT);
                } else {
                    __hip_atomic_store(&weff[u0 + t], wacc + sm.mv.cbv[KDEG] * s,
                                       __ATOMIC_RELAXED, __HIP_MEMORY_SCOPE_AGENT);
                }
            }
            __syncthreads();
            if (t == 0) bar_arrive(ws, g);
        }
    }

    // ---------------- head phase (all 256 blocks) ----------------
    // Non-chain blocks start here immediately: their GEMM overlaps the chain.
    const int b = g >> 5, vchunk = g & 31;
    __syncthreads();                       // chain blocks: done with mv union
    for (int i = t; i < F0D * HIDD; i += 256) {
        int f = i >> 6, h = i & 63;
        sm.hd.W1t[h][f] = W1[i];
    }
    __syncthreads();

    const int hg = t & 15, vg = t >> 4;
    const int vbase = vchunk * 64 + vg * 4;
    const float* Xb = X + ((size_t)b * NN + vbase) * F0D;
    float acc2[4][4] = {};
    for (int f = 0; f < F0D; f += 4) {
        float4 xr[4];
        #pragma unroll
        for (int i = 0; i < 4; ++i)
            xr[i] = *(const float4*)(Xb + (size_t)i * F0D + f);
        #pragma unroll
        for (int jj = 0; jj < 4; ++jj) {
            float4 wr = *(const float4*)(&sm.hd.W1t[hg + 16 * jj][f]);
            #pragma unroll
            for (int i = 0; i < 4; ++i)
                acc2[i][jj] += xr[i].x * wr.x + xr[i].y * wr.y
                             + xr[i].z * wr.z + xr[i].w * wr.w;
        }
    }

    // need weff now
    if (t == 0) bar_wait(ws, 128u * KDEG);
    __syncthreads();
    if (t < 64)
        sm.hd.wv[t] = __hip_atomic_load(&weff[vchunk * 64 + t],
                                        __ATOMIC_RELAXED, __HIP_MEMORY_SCOPE_AGENT);
    __syncthreads();

    float hsum[4] = {0.f, 0.f, 0.f, 0.f};
    #pragma unroll
    for (int i = 0; i < 4; ++i) {
        float we = sm.hd.wv[vg * 4 + i];
        #pragma unroll
        for (int jj = 0; jj < 4; ++jj) {
            float r = acc2[i][jj] + b1[hg + 16 * jj];
            r = r > 0.f ? r : 0.f;
            hsum[jj] += r * we;
        }
    }
    #pragma unroll
    for (int jj = 0; jj < 4; ++jj) sm.hd.redm[vg][hg + 16 * jj] = hsum[jj];
    __syncthreads();
    if (t < 64) {
        float s = 0.f;
        #pragma unroll
        for (int i = 0; i < 16; ++i) s += sm.hd.redm[i][t];
        atomicAdd(&Hg[b * 64 + t], s * (1.0f / (float)NN));
    }
    __syncthreads();
    if (t == 0) bar_arrive(ws, g);

    // ---------------- output (block 0 only) ----------------
    if (g == 0) {
        if (t == 0) bar_wait(ws, 128u * KDEG + 256u);
        __syncthreads();
        if (t < 128) {
            int o = t & 15, bb = t >> 4;
            float a3 = b2[o];
            #pragma unroll
            for (int h = 0; h < HIDD; ++h)
                a3 += __hip_atomic_load(&Hg[bb * 64 + h], __ATOMIC_RELAXED,
                                        __HIP_MEMORY_SCOPE_AGENT) * W2[h * 16 + o];
            out[bb * 16 + o] = a3;
        }
    }
}

extern "C" void kernel_launch(void* const* d_in, const int* in_sizes, int n_in,
                              void* d_out, int out_size, void* d_ws, size_t ws_size,
                              hipStream_t stream) {
    const float* X     = (const float*)d_in[0];
    const float* L     = (const float*)d_in[1];
    const float* W1    = (const float*)d_in[2];
    const float* b1    = (const float*)d_in[3];
    const float* W2    = (const float*)d_in[4];
    const float* b2    = (const float*)d_in[5];
    const float* theta = (const float*)d_in[6];
    // d_in[7] = dp = 0 -> dropout identity; ignored.
    float* outp = (float*)d_out;
    float* wsp  = (float*)d_ws;

    // zero Hg + barrier counters (floats [6144,7168))
    hipMemsetAsync((char*)d_ws + 6144 * sizeof(float), 0, 4096, stream);

    void* args[] = {(void*)&X, (void*)&L, (void*)&W1, (void*)&b1,
                    (void*)&W2, (void*)&b2, (void*)&theta, (void*)&outp, (void*)&wsp};
    hipLaunchCooperativeKernel((void*)k_fused, dim3(256), dim3(256),
                               args, 0, stream);
}

// Round 3
// 184.417 us; speedup vs baseline: 2.2954x; 1.6549x over previous
//
#include <hip/hip_runtime.h>

#define NN     2048
#define F0D    128
#define HIDD   64
#define OUTD   16
#define KDEG   10
#define NCHAIN 128      // chain blocks; each owns 16 L-columns, LDS-resident
#define COLS   16

// ws float layout:
//  [0]    p ping (2048) | [2048] p pong (2048) | [4096] weff (2048)
//  [6144] Hg (512) | [6656] barrier root (uint) | [6688+32*grp] 8 group ctrs
//  memset region: floats [6144, 7168) zeroed per launch.
//
// Barrier discipline (the round-2 lesson): NO acquire on the poll loop —
// agent-scope acquire emits buffer_inv (L2-wide invalidate) per poll on
// gfx950, which throttled the whole chip. Relaxed polls; one acquire at
// exit; release only on the arrive RMW (gives the vmcnt drain that orders
// the preceding relaxed p-stores).

__device__ __forceinline__ void bar_arrive(float* ws, int g) {
    unsigned* grp  = (unsigned*)(ws + 6688 + 32 * (g & 7));
    unsigned* root = (unsigned*)(ws + 6656);
    unsigned old = __hip_atomic_fetch_add(grp, 1u, __ATOMIC_RELEASE,
                                          __HIP_MEMORY_SCOPE_AGENT);
    if ((old & 15u) == 15u)   // 16th member of the group forwards 16 to root
        __hip_atomic_fetch_add(root, 16u, __ATOMIC_RELEASE,
                               __HIP_MEMORY_SCOPE_AGENT);
}

template <int SLP>
__device__ __forceinline__ void bar_wait(float* ws, unsigned target) {
    unsigned* root = (unsigned*)(ws + 6656);
    while (__hip_atomic_load(root, __ATOMIC_RELAXED,
                             __HIP_MEMORY_SCOPE_AGENT) < target)
        __builtin_amdgcn_s_sleep(SLP);
    (void)__hip_atomic_load(root, __ATOMIC_ACQUIRE,
                            __HIP_MEMORY_SCOPE_AGENT);   // one inv, at exit
}

__global__ __launch_bounds__(256, 1) void k_fused(
    const float* __restrict__ X, const float* __restrict__ L,
    const float* __restrict__ W1, const float* __restrict__ b1,
    const float* __restrict__ W2, const float* __restrict__ b2,
    const float* __restrict__ theta, float* __restrict__ out,
    float* __restrict__ ws)
{
    float* bp0  = ws;
    float* bp1  = ws + NN;
    float* weff = ws + 2 * NN;
    float* Hg   = ws + 3 * NN;

    __shared__ union {
        struct { float Lt[NN * COLS]; float xs[NN]; float redf[4][16]; float cbv[16]; } mv;
        struct { float W1t[64][132]; float redm[16][65]; float wv[64]; } hd;
    } sm;

    const int g = blockIdx.x;   // 256 blocks, 1 per CU (LDS-forced)
    const int t = threadIdx.x;  // 256 threads

    if (g < NCHAIN) {
        // ---------------- chain: weff = sum_j c_j (L^T)^j 1 ----------------
        const int u0 = g * COLS;

        if (t <= KDEG) {   // Bernstein -> monomial coefficients (exact binomials)
            const float C10[11] = {1,10,45,120,210,252,210,120,45,10,1};
            float acc = 0.f;
            for (int i = 0; i <= t; ++i) {
                int n = KDEG - i, r = t - i;
                long long cm = 1;
                for (int s = 1; s <= r; ++s) cm = cm * (n - r + s) / s;
                float term = theta[i] * C10[i] * (float)cm;
                if ((t - i) & 1) term = -term;
                acc += term;
            }
            sm.mv.cbv[t] = acc;
        }

        // L[:, u0:u0+16] -> LDS (128 KB), 64B-aligned segments per row
        const float4* L4  = (const float4*)L;
        float4*       Lt4 = (float4*)sm.mv.Lt;
        #pragma unroll 8
        for (int i = 0; i < 32; ++i) {
            int idx = t + 256 * i;
            int v = idx >> 2, qc = idx & 3;
            Lt4[idx] = L4[(size_t)v * (NN / 4) + (u0 >> 2) + qc];
        }
        __syncthreads();

        float wacc = 0.f;   // t < COLS: Horner acc of sum_{j<K} c_j p_j[u0+t]
        for (int j = 1; j <= KDEG; ++j) {
            if (j > 1) { if (t == 0) bar_wait<4>(ws, 128u * (j - 1)); __syncthreads(); }

            if (j > 1) {   // stage p_{j-1} (relaxed agent atomics: LLC-fresh)
                const unsigned long long* xg =
                    (const unsigned long long*)(((j - 1) & 1) ? bp1 : bp0);
                unsigned long long* xsd = (unsigned long long*)sm.mv.xs;
                #pragma unroll
                for (int i = 0; i < 4; ++i)
                    xsd[t + 256 * i] = __hip_atomic_load(&xg[t + 256 * i],
                        __ATOMIC_RELAXED, __HIP_MEMORY_SCOPE_AGENT);
            }
            __syncthreads();

            const int qc = t & 3, r = t >> 2;   // 64 row-streams x 4 col-quads
            float4 acc = make_float4(0.f, 0.f, 0.f, 0.f);
            #pragma unroll 8
            for (int k = 0; k < 32; ++k) {
                int v = r + 64 * k;
                float xv = (j == 1) ? 1.0f : sm.mv.xs[v];
                float4 lv = Lt4[v * 4 + qc];
                acc.x += lv.x * xv; acc.y += lv.y * xv;
                acc.z += lv.z * xv; acc.w += lv.w * xv;
            }
            #pragma unroll
            for (int m = 4; m <= 32; m <<= 1) {
                acc.x += __shfl_xor(acc.x, m); acc.y += __shfl_xor(acc.y, m);
                acc.z += __shfl_xor(acc.z, m); acc.w += __shfl_xor(acc.w, m);
            }
            int lane = t & 63, wid = t >> 6;
            if (lane < 4) *(float4*)&sm.mv.redf[wid][lane * 4] = acc;
            __syncthreads();

            if (t < COLS) {
                float s = sm.mv.redf[0][t] + sm.mv.redf[1][t]
                        + sm.mv.redf[2][t] + sm.mv.redf[3][t];
                float pprev = (j == 1) ? 1.0f : sm.mv.xs[u0 + t];
                wacc += sm.mv.cbv[j - 1] * pprev;
                if (j < KDEG) {
                    float* xn = (j & 1) ? bp1 : bp0;
                    __hip_atomic_store(&xn[u0 + t], s, __ATOMIC_RELAXED,
                                       __HIP_MEMORY_SCOPE_AGENT);
                } else {
                    __hip_atomic_store(&weff[u0 + t], wacc + sm.mv.cbv[KDEG] * s,
                                       __ATOMIC_RELAXED, __HIP_MEMORY_SCOPE_AGENT);
                }
            }
            __syncthreads();   // drains each wave's stores before the arrive
            if (t == 0) bar_arrive(ws, g);
        }

        // ---------------- output (chain block 0 only) ----------------
        if (g == 0) {
            if (t == 0) bar_wait<8>(ws, 128u * KDEG + 128u);  // head blocks done
            __syncthreads();
            if (t < 128) {
                int o = t & 15, bb = t >> 4;
                float a3 = b2[o];
                #pragma unroll
                for (int h = 0; h < HIDD; ++h)
                    a3 += __hip_atomic_load(&Hg[bb * 64 + h], __ATOMIC_RELAXED,
                                            __HIP_MEMORY_SCOPE_AGENT) * W2[h * 16 + o];
                out[bb * 16 + o] = a3;
            }
        }
        return;
    }

    // ---------------- head (128 blocks, 2 units each, overlaps chain) --------
    // unit A = (bA = u>>5, vchunk), unit B = (bA+4, same vchunk)
    const int u = g - NCHAIN;
    const int vchunk = u & 31, bA = u >> 5, bB = bA + 4;

    for (int i = t; i < F0D * HIDD; i += 256) {
        int f = i >> 6, h = i & 63;
        sm.hd.W1t[h][f] = W1[i];
    }
    __syncthreads();

    const int hg = t & 15, vg = t >> 4;
    const int vbase = vchunk * 64 + vg * 4;
    const float* XA = X + ((size_t)bA * NN + vbase) * F0D;
    const float* XB = X + ((size_t)bB * NN + vbase) * F0D;
    float accA[4][4] = {}, accB[4][4] = {};
    for (int f = 0; f < F0D; f += 4) {
        float4 xa[4], xb[4];
        #pragma unroll
        for (int i = 0; i < 4; ++i) {
            xa[i] = *(const float4*)(XA + (size_t)i * F0D + f);
            xb[i] = *(const float4*)(XB + (size_t)i * F0D + f);
        }
        #pragma unroll
        for (int jj = 0; jj < 4; ++jj) {
            float4 wr = *(const float4*)(&sm.hd.W1t[hg + 16 * jj][f]);
            #pragma unroll
            for (int i = 0; i < 4; ++i) {
                accA[i][jj] += xa[i].x * wr.x + xa[i].y * wr.y
                             + xa[i].z * wr.z + xa[i].w * wr.w;
                accB[i][jj] += xb[i].x * wr.x + xb[i].y * wr.y
                             + xb[i].z * wr.z + xb[i].w * wr.w;
            }
        }
    }

    // wait for weff (coarse poll: don't pollute LLC while the chain runs)
    if (t == 0) bar_wait<16>(ws, 128u * KDEG);
    __syncthreads();
    if (t < 64)
        sm.hd.wv[t] = __hip_atomic_load(&weff[vchunk * 64 + t],
                                        __ATOMIC_RELAXED, __HIP_MEMORY_SCOPE_AGENT);
    __syncthreads();

    float hsA[4] = {0.f,0.f,0.f,0.f}, hsB[4] = {0.f,0.f,0.f,0.f};
    #pragma unroll
    for (int i = 0; i < 4; ++i) {
        float we = sm.hd.wv[vg * 4 + i];
        #pragma unroll
        for (int jj = 0; jj < 4; ++jj) {
            float rA = accA[i][jj] + b1[hg + 16 * jj];
            float rB = accB[i][jj] + b1[hg + 16 * jj];
            rA = rA > 0.f ? rA : 0.f;
            rB = rB > 0.f ? rB : 0.f;
            hsA[jj] += rA * we;
            hsB[jj] += rB * we;
        }
    }
    #pragma unroll
    for (int jj = 0; jj < 4; ++jj) sm.hd.redm[vg][hg + 16 * jj] = hsA[jj];
    __syncthreads();
    if (t < 64) {
        float s = 0.f;
        #pragma unroll
        for (int i = 0; i < 16; ++i) s += sm.hd.redm[i][t];
        atomicAdd(&Hg[bA * 64 + t], s * (1.0f / (float)NN));
    }
    __syncthreads();
    #pragma unroll
    for (int jj = 0; jj < 4; ++jj) sm.hd.redm[vg][hg + 16 * jj] = hsB[jj];
    __syncthreads();
    if (t < 64) {
        float s = 0.f;
        #pragma unroll
        for (int i = 0; i < 16; ++i) s += sm.hd.redm[i][t];
        atomicAdd(&Hg[bB * 64 + t], s * (1.0f / (float)NN));
    }
    __syncthreads();
    if (t == 0) bar_arrive(ws, g);
}

extern "C" void kernel_launch(void* const* d_in, const int* in_sizes, int n_in,
                              void* d_out, int out_size, void* d_ws, size_t ws_size,
                              hipStream_t stream) {
    const float* X     = (const float*)d_in[0];
    const float* L     = (const float*)d_in[1];
    const float* W1    = (const float*)d_in[2];
    const float* b1    = (const float*)d_in[3];
    const float* W2    = (const float*)d_in[4];
    const float* b2    = (const float*)d_in[5];
    const float* theta = (const float*)d_in[6];
    // d_in[7] = dp = 0 -> dropout identity; ignored.
    float* outp = (float*)d_out;
    float* wsp  = (float*)d_ws;

    // zero Hg + barrier counters (floats [6144, 7168))
    hipMemsetAsync((char*)d_ws + 6144 * sizeof(float), 0, 4096, stream);

    void* args[] = {(void*)&X, (void*)&L, (void*)&W1, (void*)&b1,
                    (void*)&W2, (void*)&b2, (void*)&theta, (void*)&outp, (void*)&wsp};
    hipLaunchCooperativeKernel((void*)k_fused, dim3(256), dim3(256),
                               args, 0, stream);
}

// Round 4
// 138.226 us; speedup vs baseline: 3.0625x; 1.3342x over previous
//
#include <hip/hip_runtime.h>

#define NN     2048
#define F0D    128
#define HIDD   64
#define OUTD   16
#define KDEG   10
#define NCHAIN 128      // chain blocks; each owns 16 L-columns, LDS-resident
#define COLS   16

// ws float layout:
//  [0]    p ping (2048) | [2048] p pong (2048) | [4096] weff (2048)
//  [6144] Hg (512) | [6656] barrier root (uint) | [6688+32*grp] 8 group ctrs
//  memset region: floats [6144, 7168) zeroed per launch (Hg + counters).
//
// Regular (non-cooperative) launch: grid(256) == CU count and 139.7 KB LDS
// forces 1 block/CU, so all blocks are co-resident by construction. The
// cooperative launch path cost ~75 us of fixed harness overhead (r1-r3 gap
// kernel-vs-dur was 91/98/104 us vs ~25 us for regular dispatches in r0).
//
// Barrier discipline (r2+r3 lessons combined): cross-block data ONLY moves
// through agent-scope relaxed atomics (sc1, serviced at MALL, vmcnt-ordered),
// so the barrier needs NO release (buffer_wbl2: per-XCD L2 writeback) and NO
// acquire (buffer_inv: L2 invalidate). Arrive = s_waitcnt vmcnt(0) + relaxed
// fetch_add; wait = relaxed poll with s_sleep. Wrap-safe signed compare.

__device__ __forceinline__ void bar_arrive(float* ws, int g) {
    asm volatile("s_waitcnt vmcnt(0)" ::: "memory");
    unsigned* grp  = (unsigned*)(ws + 6688 + 32 * (g & 7));
    unsigned* root = (unsigned*)(ws + 6656);
    unsigned old = __hip_atomic_fetch_add(grp, 1u, __ATOMIC_RELAXED,
                                          __HIP_MEMORY_SCOPE_AGENT);
    if ((old & 15u) == 15u)   // 16th member of the group forwards 16 to root
        __hip_atomic_fetch_add(root, 16u, __ATOMIC_RELAXED,
                               __HIP_MEMORY_SCOPE_AGENT);
}

template <int SLP>
__device__ __forceinline__ void bar_wait(float* ws, unsigned target) {
    unsigned* root = (unsigned*)(ws + 6656);
    while ((int)(__hip_atomic_load(root, __ATOMIC_RELAXED,
                                   __HIP_MEMORY_SCOPE_AGENT) - target) < 0)
        __builtin_amdgcn_s_sleep(SLP);
    asm volatile("" ::: "memory");   // compiler fence only; no cache maintenance
}

__global__ __launch_bounds__(256, 1) void k_fused(
    const float* __restrict__ X, const float* __restrict__ L,
    const float* __restrict__ W1, const float* __restrict__ b1,
    const float* __restrict__ W2, const float* __restrict__ b2,
    const float* __restrict__ theta, float* __restrict__ out,
    float* __restrict__ ws)
{
    float* bp0  = ws;
    float* bp1  = ws + NN;
    float* weff = ws + 2 * NN;
    float* Hg   = ws + 3 * NN;

    __shared__ union {
        struct { float Lt[NN * COLS]; float xs[NN]; float redf[4][16]; float cbv[16]; } mv;
        struct { float W1t[64][132]; float redm[16][65]; float wv[64]; } hd;
    } sm;

    const int g = blockIdx.x;   // 256 blocks, 1 per CU (LDS-forced)
    const int t = threadIdx.x;  // 256 threads

    if (g < NCHAIN) {
        // ---------------- chain: weff = sum_j c_j (L^T)^j 1 ----------------
        const int u0 = g * COLS;

        if (t <= KDEG) {   // Bernstein -> monomial coefficients (exact binomials)
            const float C10[11] = {1,10,45,120,210,252,210,120,45,10,1};
            float acc = 0.f;
            for (int i = 0; i <= t; ++i) {
                int n = KDEG - i, r = t - i;
                long long cm = 1;
                for (int s = 1; s <= r; ++s) cm = cm * (n - r + s) / s;
                float term = theta[i] * C10[i] * (float)cm;
                if ((t - i) & 1) term = -term;
                acc += term;
            }
            sm.mv.cbv[t] = acc;
        }

        // L[:, u0:u0+16] -> LDS (128 KB), 64B-aligned segments per row
        const float4* L4  = (const float4*)L;
        float4*       Lt4 = (float4*)sm.mv.Lt;
        #pragma unroll 8
        for (int i = 0; i < 32; ++i) {
            int idx = t + 256 * i;
            int v = idx >> 2, qc = idx & 3;
            Lt4[idx] = L4[(size_t)v * (NN / 4) + (u0 >> 2) + qc];
        }
        __syncthreads();

        float wacc = 0.f;   // t < COLS: Horner acc of sum_{j<K} c_j p_j[u0+t]
        for (int j = 1; j <= KDEG; ++j) {
            if (j > 1) {
                if (t == 0) bar_wait<1>(ws, 128u * (j - 1));
                __syncthreads();
                // stage p_{j-1} (relaxed sc1 atomics: MALL-fresh)
                const unsigned long long* xg =
                    (const unsigned long long*)(((j - 1) & 1) ? bp1 : bp0);
                unsigned long long* xsd = (unsigned long long*)sm.mv.xs;
                #pragma unroll
                for (int i = 0; i < 4; ++i)
                    xsd[t + 256 * i] = __hip_atomic_load(&xg[t + 256 * i],
                        __ATOMIC_RELAXED, __HIP_MEMORY_SCOPE_AGENT);
            }
            __syncthreads();

            const int qc = t & 3, r = t >> 2;   // 64 row-streams x 4 col-quads
            float4 acc = make_float4(0.f, 0.f, 0.f, 0.f);
            #pragma unroll 8
            for (int k = 0; k < 32; ++k) {
                int v = r + 64 * k;
                float xv = (j == 1) ? 1.0f : sm.mv.xs[v];
                float4 lv = Lt4[v * 4 + qc];
                acc.x += lv.x * xv; acc.y += lv.y * xv;
                acc.z += lv.z * xv; acc.w += lv.w * xv;
            }
            #pragma unroll
            for (int m = 4; m <= 32; m <<= 1) {
                acc.x += __shfl_xor(acc.x, m); acc.y += __shfl_xor(acc.y, m);
                acc.z += __shfl_xor(acc.z, m); acc.w += __shfl_xor(acc.w, m);
            }
            int lane = t & 63, wid = t >> 6;
            if (lane < 4) *(float4*)&sm.mv.redf[wid][lane * 4] = acc;
            __syncthreads();

            if (t < COLS) {
                float s = sm.mv.redf[0][t] + sm.mv.redf[1][t]
                        + sm.mv.redf[2][t] + sm.mv.redf[3][t];
                float pprev = (j == 1) ? 1.0f : sm.mv.xs[u0 + t];
                wacc += sm.mv.cbv[j - 1] * pprev;
                if (j < KDEG) {
                    float* xn = (j & 1) ? bp1 : bp0;
                    __hip_atomic_store(&xn[u0 + t], s, __ATOMIC_RELAXED,
                                       __HIP_MEMORY_SCOPE_AGENT);
                } else {
                    __hip_atomic_store(&weff[u0 + t], wacc + sm.mv.cbv[KDEG] * s,
                                       __ATOMIC_RELAXED, __HIP_MEMORY_SCOPE_AGENT);
                }
            }
            __syncthreads();   // compiler emits vmcnt(0) drain before s_barrier
            if (t == 0) bar_arrive(ws, g);
        }

        // ---------------- output (chain block 0 only) ----------------
        if (g == 0) {
            if (t == 0) bar_wait<8>(ws, 128u * KDEG + 128u);  // head blocks done
            __syncthreads();
            if (t < 128) {
                int o = t & 15, bb = t >> 4;
                float a3 = b2[o];
                #pragma unroll
                for (int h = 0; h < HIDD; ++h)
                    a3 += __hip_atomic_load(&Hg[bb * 64 + h], __ATOMIC_RELAXED,
                                            __HIP_MEMORY_SCOPE_AGENT) * W2[h * 16 + o];
                out[bb * 16 + o] = a3;
            }
        }
        return;
    }

    // ---------------- head (128 blocks, 2 units each, overlaps chain) --------
    const int u = g - NCHAIN;
    const int vchunk = u & 31, bA = u >> 5, bB = bA + 4;

    for (int i = t; i < F0D * HIDD; i += 256) {
        int f = i >> 6, h = i & 63;
        sm.hd.W1t[h][f] = W1[i];
    }
    __syncthreads();

    const int hg = t & 15, vg = t >> 4;
    const int vbase = vchunk * 64 + vg * 4;
    const float* XA = X + ((size_t)bA * NN + vbase) * F0D;
    const float* XB = X + ((size_t)bB * NN + vbase) * F0D;
    float accA[4][4] = {}, accB[4][4] = {};
    for (int f = 0; f < F0D; f += 4) {
        float4 xa[4], xb[4];
        #pragma unroll
        for (int i = 0; i < 4; ++i) {
            xa[i] = *(const float4*)(XA + (size_t)i * F0D + f);
            xb[i] = *(const float4*)(XB + (size_t)i * F0D + f);
        }
        #pragma unroll
        for (int jj = 0; jj < 4; ++jj) {
            float4 wr = *(const float4*)(&sm.hd.W1t[hg + 16 * jj][f]);
            #pragma unroll
            for (int i = 0; i < 4; ++i) {
                accA[i][jj] += xa[i].x * wr.x + xa[i].y * wr.y
                             + xa[i].z * wr.z + xa[i].w * wr.w;
                accB[i][jj] += xb[i].x * wr.x + xb[i].y * wr.y
                             + xb[i].z * wr.z + xb[i].w * wr.w;
            }
        }
    }

    // wait for weff
    if (t == 0) bar_wait<2>(ws, 128u * KDEG);
    __syncthreads();
    if (t < 64)
        sm.hd.wv[t] = __hip_atomic_load(&weff[vchunk * 64 + t],
                                        __ATOMIC_RELAXED, __HIP_MEMORY_SCOPE_AGENT);
    __syncthreads();

    float hsA[4] = {0.f,0.f,0.f,0.f}, hsB[4] = {0.f,0.f,0.f,0.f};
    #pragma unroll
    for (int i = 0; i < 4; ++i) {
        float we = sm.hd.wv[vg * 4 + i];
        #pragma unroll
        for (int jj = 0; jj < 4; ++jj) {
            float rA = accA[i][jj] + b1[hg + 16 * jj];
            float rB = accB[i][jj] + b1[hg + 16 * jj];
            rA = rA > 0.f ? rA : 0.f;
            rB = rB > 0.f ? rB : 0.f;
            hsA[jj] += rA * we;
            hsB[jj] += rB * we;
        }
    }
    #pragma unroll
    for (int jj = 0; jj < 4; ++jj) sm.hd.redm[vg][hg + 16 * jj] = hsA[jj];
    __syncthreads();
    if (t < 64) {
        float s = 0.f;
        #pragma unroll
        for (int i = 0; i < 16; ++i) s += sm.hd.redm[i][t];
        atomicAdd(&Hg[bA * 64 + t], s * (1.0f / (float)NN));
    }
    __syncthreads();
    #pragma unroll
    for (int jj = 0; jj < 4; ++jj) sm.hd.redm[vg][hg + 16 * jj] = hsB[jj];
    __syncthreads();
    if (t < 64) {
        float s = 0.f;
        #pragma unroll
        for (int i = 0; i < 16; ++i) s += sm.hd.redm[i][t];
        atomicAdd(&Hg[bB * 64 + t], s * (1.0f / (float)NN));
    }
    __syncthreads();   // drains the atomicAdds (vmcnt) before the arrive
    if (t == 0) bar_arrive(ws, g);
}

extern "C" void kernel_launch(void* const* d_in, const int* in_sizes, int n_in,
                              void* d_out, int out_size, void* d_ws, size_t ws_size,
                              hipStream_t stream) {
    const float* X     = (const float*)d_in[0];
    const float* L     = (const float*)d_in[1];
    const float* W1    = (const float*)d_in[2];
    const float* b1    = (const float*)d_in[3];
    const float* W2    = (const float*)d_in[4];
    const float* b2    = (const float*)d_in[5];
    const float* theta = (const float*)d_in[6];
    // d_in[7] = dp = 0 -> dropout identity; ignored.
    float* outp = (float*)d_out;
    float* wsp  = (float*)d_ws;

    // zero Hg + barrier counters (floats [6144, 7168))
    hipMemsetAsync((char*)d_ws + 6144 * sizeof(float), 0, 4096, stream);

    hipLaunchKernelGGL(k_fused, dim3(256), dim3(256), 0, stream,
                       X, L, W1, b1, W2, b2, theta, outp, wsp);
}